// Round 2
// baseline (191.654 us; speedup 1.0000x reference)
//
#include <hip/hip_runtime.h>
#include <hip/hip_bf16.h>

#define NATOM 128
#define NB    127
#define D0    25
#define D1    50
#define D2    100
#define H0STR 40     // halves; 80 B rows -> b128 A-frag reads 2-way (free); cols 32..39 unused
#define H1STR 56     // halves; 112 B rows; cols 50..55 zero-pad (lq=3 K-frag remapped)
#define MROWS 176    // worst case: sum 16*ceil(c_t/16) = 176 rows
#define W1H_HALVES (16 * 50 * 32)     // 25600  (K 25 -> 32, zero-padded)
#define W2H_HALVES (16 * 100 * 64)    // 102400 (K 50 -> 64, zero-padded)
#define CT 2.8853900817779268f        // 2*log2(e); tanh(x)=1-2/(exp2(CT*x)+1)

typedef _Float16 half8 __attribute__((ext_vector_type(8)));  // 8 fp16 = 4 VGPRs
typedef __attribute__((ext_vector_type(4))) float f32x4;

__device__ __forceinline__ float exp2_hw(float x) {
#if defined(__has_builtin)
#if __has_builtin(__builtin_amdgcn_exp2f)
    return __builtin_amdgcn_exp2f(x);        // raw v_exp_f32 (exp2 semantics)
#else
    return __expf(0.6931471805599453f * x);
#endif
#else
    return __expf(0.6931471805599453f * x);
#endif
}

// tanh(x) with PRE-SCALED argument y = CT*x (CT folded into weights/bias):
// tanh(x) = 1 - 2/(exp2(y)+1). exp2->add->rcp->fma.
__device__ __forceinline__ float tanh_pre(float y) {
    float e = exp2_hw(y);
    return 1.0f - 2.0f * __builtin_amdgcn_rcpf(e + 1.0f);
}

// ---- one-shot (per launch) fp32 -> fp16 weight repack into d_ws ----------
// W1h[idx][o][k32], W2h[idx][o][k64]; values pre-scaled by CT so the MFMA
// accumulator is already the exp2 argument. |CT*W| <= 0.6 -> fp16-safe.
__global__ void cvt_kernel(const float* __restrict__ W1,
                           const float* __restrict__ W2,
                           unsigned int* __restrict__ ws) {
    const int i = blockIdx.x * 256 + threadIdx.x;   // dword index
    if (i >= (W1H_HALVES + W2H_HALVES) / 2) return;
    float v0, v1;
    if (i < W1H_HALVES / 2) {
        const int s = 2 * i;
        const int row = s >> 5, kk = s & 31;        // row = idx*50 + o
        const float* base = W1 + row * D0;
        v0 = (kk < D0) ? base[kk] : 0.f;
        v1 = (kk + 1 < D0) ? base[kk + 1] : 0.f;
    } else {
        const int s = 2 * i - W1H_HALVES;
        const int row = s >> 6, kk = s & 63;        // row = idx*100 + o
        const float* base = W2 + row * D1;
        v0 = (kk < D1) ? base[kk] : 0.f;
        v1 = (kk + 1 < D1) ? base[kk + 1] : 0.f;
    }
    union { _Float16 h[2]; unsigned int u; } cv;
    cv.h[0] = (_Float16)(CT * v0);                  // RNE, range-safe
    cv.h[1] = (_Float16)(CT * v1);
    ws[i] = cv.u;
}

__global__ __launch_bounds__(256, 1) void feat_kernel(
    const float* __restrict__ coords,
    const int*   __restrict__ types,
    const float* __restrict__ W0, const float* __restrict__ B0,
    const float* __restrict__ B1, const float* __restrict__ B2,
    const _Float16* __restrict__ W1h, const _Float16* __restrict__ W2h,
    float* __restrict__ out)
{
    // 19712 + 14080 + 2816 + 400 + 800 + 32 = 37840 B -> 4 blocks/CU, 16 waves
    __shared__ __attribute__((aligned(16))) _Float16 H1f[MROWS][H1STR];
    // H0f's last read is before the 2a->2b barrier; Ms is zeroed after it.
    __shared__ union __attribute__((aligned(16))) {
        _Float16 H0f[MROWS][H0STR];
        float    Ms[3][112];
    } u;
    // env_a packed per row: {ax, ay, az, 0} -> one broadcast b128 read in 2b.
    __shared__ __attribute__((aligned(16))) float Ep[MROWS][4];
    __shared__ _Float16 PB1[4][D1];     // CT-scaled fp16 biases
    __shared__ _Float16 PB2[4][D2];
    __shared__ int cnt[2][4];           // per-wave type counts (waves 0,1)

    const int bn = blockIdx.x;    // b*128 + n
    const int b  = bn >> 7;
    const int n  = bn & 127;
    const int k  = threadIdx.x;   // 0..255
    const int wv = k >> 6;        // wave 0..3
    const int lq = (k >> 4) & 3;  // quad within wave
    const int ln = k & 15;
    const int lane = k & 63;
    const int tn  = types[n];

    // ---- stage CT-scaled fp16 bias tables for this center type
    for (int i = k; i < 600; i += 256) {
        if (i < 200) PB1[0][i] = (_Float16)(CT * B1[tn * 200 + i]);
        else         PB2[0][i - 200] = (_Float16)(CT * B2[tn * 400 + (i - 200)]);
    }

    // ---- ballot-based type counts + stable ranks.
    // Threads 128+i mirror thread i's neighbor: waves {0,2} and {1,3} have
    // identical lane<->neighbor maps, so ranks come free for both halves.
    int tj = -1, j0 = 0, jj = -1;
    if (k < NB) jj = k;
    else if (k >= 128 && k < 128 + NB) jj = k - 128;
    if (jj >= 0) { j0 = jj + (jj >= n ? 1 : 0); tj = types[j0]; }
    const unsigned long long bm0 = __ballot(tj == 0);
    const unsigned long long bm1 = __ballot(tj == 1);
    const unsigned long long bm2 = __ballot(tj == 2);
    const unsigned long long bm3 = __ballot(tj == 3);
    if (lane == 0 && wv < 2) {
        cnt[wv][0] = __popcll(bm0); cnt[wv][1] = __popcll(bm1);
        cnt[wv][2] = __popcll(bm2); cnt[wv][3] = __popcll(bm3);
    }
    int sameBefore = 0;
    if (jj >= 0) {
        const unsigned long long mym =
            (tj == 0) ? bm0 : (tj == 1) ? bm1 : (tj == 2) ? bm2 : bm3;
        sameBefore = __popcll(mym & ((1ULL << lane) - 1ULL));
    }
    __syncthreads();

    const int c0 = cnt[0][0] + cnt[1][0];
    const int c1 = cnt[0][1] + cnt[1][1];
    const int c2 = cnt[0][2] + cnt[1][2];
    const int c3 = cnt[0][3] + cnt[1][3];
    const int ps1 = (c0 + 15) & ~15;
    const int ps2 = ps1 + ((c1 + 15) & ~15);
    const int ps3 = ps2 + ((c2 + 15) & ~15);
    const int mtA = (c0 + 15) >> 4, mtB = (c1 + 15) >> 4;
    const int mtC = (c2 + 15) >> 4, mtD = (c3 + 15) >> 4;
    const int TT  = mtA + mtB + mtC + mtD;      // total m-tiles (<= 11)

    // ======== phase 1: geometry + layer 0, split across ALL 256 threads ====
    // A-half (k<128): Ep + h0[0..11] (3 uint2 stores, dwords 0..5).
    // B-half: h0[12..24] + K-pad (5 uint2 stores, dwords 6..15). No b16/b32.
    if (jj >= 0) {
        const int idx = (tn << 2) | tj;
        const int pst = (tj == 0) ? 0 : (tj == 1) ? ps1 : (tj == 2) ? ps2 : ps3;
        const int pr  = pst + sameBefore + ((wv & 1) ? cnt[0][tj] : 0);

        const float cx = coords[(b * NATOM + n) * 3 + 0];
        const float cy = coords[(b * NATOM + n) * 3 + 1];
        const float cz = coords[(b * NATOM + n) * 3 + 2];
        const float dx = cx - coords[(b * NATOM + j0) * 3 + 0];
        const float dy = cy - coords[(b * NATOM + j0) * 3 + 1];
        const float dz = cz - coords[(b * NATOM + j0) * 3 + 2];
        const float d2   = dx * dx + dy * dy + dz * dz;
        const float inv  = rsqrtf(d2);         // 1/d (= env_r)
        const float inv2 = inv * inv;
        const float invc = CT * inv;           // pre-scaled tanh argument

        const float* w  = W0 + idx * D0;
        const float* bb = B0 + idx * D0;
        uint2* dst2 = (uint2*)&u.H0f[pr][0];

        if (k < 128) {                         // A-half: Ep + h0[0..11]
            float4 ev = {dx * inv2, dy * inv2, dz * inv2, 0.f};
            *(float4*)&Ep[pr][0] = ev;
            unsigned int dv[6];
            #pragma unroll
            for (int o = 0; o < 12; o += 2) {
                union { _Float16 h[2]; unsigned int v; } cv;
                cv.h[0] = (_Float16)tanh_pre(fmaf(w[o], invc, CT * bb[o]));
                cv.h[1] = (_Float16)tanh_pre(fmaf(w[o + 1], invc, CT * bb[o + 1]));
                dv[o >> 1] = cv.v;
            }
            uint2 s0; s0.x = dv[0]; s0.y = dv[1]; dst2[0] = s0;
            uint2 s1; s1.x = dv[2]; s1.y = dv[3]; dst2[1] = s1;
            uint2 s2; s2.x = dv[4]; s2.y = dv[5]; dst2[2] = s2;
        } else {                               // B-half: h0[12..24] + K-pad
            _Float16 hv[13];
            #pragma unroll
            for (int q = 0; q < 13; ++q)
                hv[q] = (_Float16)tanh_pre(fmaf(w[12 + q], invc, CT * bb[12 + q]));
            unsigned int dv[7];
            #pragma unroll
            for (int q = 0; q < 6; ++q) {
                union { _Float16 h[2]; unsigned int v; } cv;
                cv.h[0] = hv[2 * q]; cv.h[1] = hv[2 * q + 1];
                dv[q] = cv.v;                  // dwords 6..11 (cols 12..23)
            }
            { union { _Float16 h[2]; unsigned int v; } cl;
              cl.h[0] = hv[12]; cl.h[1] = (_Float16)0.f; dv[6] = cl.v; } // col 24 + pad
            uint2 s3; s3.x = dv[0]; s3.y = dv[1]; dst2[3] = s3;
            uint2 s4; s4.x = dv[2]; s4.y = dv[3]; dst2[4] = s4;
            uint2 s5; s5.x = dv[4]; s5.y = dv[5]; dst2[5] = s5;
            uint2 s6; s6.x = dv[6]; s6.y = 0u;   dst2[6] = s6;   // cols 24..27
            uint2 s7; s7.x = 0u;    s7.y = 0u;   dst2[7] = s7;   // cols 28..31
        }
    }
    // ---- pad-ROW zeroing: <=49 rows, spare B-side threads. Zero h0 K-range
    // (cols 0..31; 32..39 never read) + Ep row (Mc mask).
    if (k >= 128 && k < 255) {
        const int i = k - 128;
        const int p0 = ((c0 + 15) & ~15) - c0;
        const int p1 = ((c1 + 15) & ~15) - c1;
        const int p2 = ((c2 + 15) & ~15) - c2;
        const int p3 = ((c3 + 15) & ~15) - c3;
        int row = -1;
        if (i < p0)                row = c0 + i;
        else if (i < p0 + p1)      row = ps1 + c1 + (i - p0);
        else if (i < p0 + p1 + p2) row = ps2 + c2 + (i - p0 - p1);
        else if (i < p0 + p1 + p2 + p3)
                                   row = ps3 + c3 + (i - p0 - p1 - p2);
        if (row >= 0) {
            uint2* pz = (uint2*)&u.H0f[row][0];
            const uint2 z2 = {0u, 0u};
            #pragma unroll
            for (int q = 0; q < 8; ++q) pz[q] = z2;
            float4 z4 = {0.f, 0.f, 0.f, 0.f};
            *(float4*)&Ep[row][0] = z4;
        }
    }
    __syncthreads();

    // ======== phase 2a: layer 1 via MFMA (25 -> 50), K padded to 32 ========
    // Always-store (ov1 ? h : 0) fills H1f pad cols 50..55; cols 56..63 of
    // the logical K=64 don't exist (lq=3 B-frag rows of W2h are zero).
    {
        const int o1   = wv * 16 + ln;         // 0..63
        const bool ov1 = (o1 < D1);
        const bool st1 = (o1 < H1STR);         // only cols 0..55 exist
        const int o1c  = ov1 ? o1 : 0;         // clamp: pad lanes load row 0
        const int rres1 = ((o1 < D0) ? o1 : (o1 - D0)) & 31;  // in-row clamp
        #pragma unroll
        for (int t = 0; t < 4; ++t) {
            const int cnt_t = (t == 0) ? c0 : (t == 1) ? c1 : (t == 2) ? c2 : c3;
            if (cnt_t == 0) continue;
            const int ps  = (t == 0) ? 0 : (t == 1) ? ps1 : (t == 2) ? ps2 : ps3;
            const int idx = (tn << 2) | t;
            const half8 bf =
                *(const half8*)(W1h + (idx * 50 + o1c) * 32 + lq * 8);
            const float b1v = ov1 ? (float)PB1[t][o1c] : 0.f;
            const int mtiles = (cnt_t + 15) >> 4;
            for (int mt = 0; mt < mtiles; ++mt) {
                const int mb = ps + mt * 16;
                const half8 af = *(const half8*)(&u.H0f[mb + ln][lq * 8]);
                f32x4 d = {b1v, b1v, b1v, b1v};        // bias as C-operand
                d = __builtin_amdgcn_mfma_f32_16x16x32_f16(af, bf, d, 0, 0, 0);
                #pragma unroll
                for (int r = 0; r < 4; ++r) {
                    const int m = mb + lq * 4 + r;
                    const _Float16 h16 =
                        (_Float16)tanh_pre(d[r]) + u.H0f[m][rres1];
                    if (st1) H1f[m][o1] = ov1 ? h16 : (_Float16)0.f;
                }
            }
        }
    }
    __syncthreads();
    // ---- H0f is dead; union region becomes Ms. Zero it (atomic targets).
    for (int i = k; i < 336; i += 256) (&u.Ms[0][0])[i] = 0.f;
    __syncthreads();

    // ======== phase 2b: layer 2 via MFMA (50 -> 100) + fused M-reduce ======
    // Balanced: each wave owns one full group (nt = wv); waves 0..2 also run
    // groups 4..6 minus the last S tiles; wave 3 covers those S tails.
    // Groups 0..3 flush with plain stores; 4..6 with LDS atomicAdd.
    const int off1 = (lq == 3) ? 32 : (32 + lq * 8);  // lq=3 K-rows of W2h are 0

    auto run_group = [&](int nt, int glo, int ghi, bool at) {
        const int o  = nt * 16 + ln;           // output neuron
        const bool ov = (o < D2);
        const int oc = ov ? o : (D2 - 1);
        const int rres = oc % D1;              // residual column
        float Mc0 = 0.f, Mc1 = 0.f, Mc2 = 0.f;
        int base = 0;
        #pragma unroll
        for (int t = 0; t < 4; ++t) {
            const int mtl = (t == 0) ? mtA : (t == 1) ? mtB : (t == 2) ? mtC : mtD;
            const int lo = (glo - base > 0) ? (glo - base) : 0;
            const int hi = (ghi - base < mtl) ? (ghi - base) : mtl;
            base += mtl;
            if (lo >= hi) continue;
            const int ps  = (t == 0) ? 0 : (t == 1) ? ps1 : (t == 2) ? ps2 : ps3;
            const int idx = (tn << 2) | t;
            const _Float16* wr = W2h + (idx * 100 + oc) * 64;
            const half8 bf0 = *(const half8*)(wr + lq * 8);        // k<32
            const half8 bf1 = *(const half8*)(wr + 32 + lq * 8);   // K-pad=0 @lq=3
            const float b2n = (float)PB2[t][oc];
            for (int mt = lo; mt < hi; ++mt) {
                const int mb = ps + mt * 16;
                const _Float16* arow = &H1f[mb + ln][0];
                const half8 af0 = *(const half8*)(arow + lq * 8);
                const half8 af1 = *(const half8*)(arow + off1);
                f32x4 d = {b2n, b2n, b2n, b2n};        // bias as C-operand
                d = __builtin_amdgcn_mfma_f32_16x16x32_f16(af0, bf0, d, 0, 0, 0);
                d = __builtin_amdgcn_mfma_f32_16x16x32_f16(af1, bf1, d, 0, 0, 0);
                const int mq = mb + lq * 4;
                #pragma unroll
                for (int r = 0; r < 4; ++r) {          // C/D: row = quad*4+r
                    const int m = mq + r;
                    const float4 e4 = *(const float4*)&Ep[m][0];
                    const float g = tanh_pre(d[r]) + (float)H1f[m][rres];
                    Mc0 = fmaf(e4.x, g, Mc0);
                    Mc1 = fmaf(e4.y, g, Mc1);
                    Mc2 = fmaf(e4.z, g, Mc2);
                }
            }
        }
        // reduce across the 4 quads (rows); lanes differ only in lq
        Mc0 += __shfl_xor(Mc0, 16, 64); Mc1 += __shfl_xor(Mc1, 16, 64);
        Mc2 += __shfl_xor(Mc2, 16, 64);
        Mc0 += __shfl_xor(Mc0, 32, 64); Mc1 += __shfl_xor(Mc1, 32, 64);
        Mc2 += __shfl_xor(Mc2, 32, 64);
        if (lq == 0 && ov) {
            if (at) {
                atomicAdd(&u.Ms[0][o], Mc0);
                atomicAdd(&u.Ms[1][o], Mc1);
                atomicAdd(&u.Ms[2][o], Mc2);
            } else {
                u.Ms[0][o] = Mc0; u.Ms[1][o] = Mc1; u.Ms[2][o] = Mc2;
            }
        }
    };

    const int S = (TT + 2) >> 2;               // tail tiles donated to wave 3
    run_group(wv, 0, TT, false);               // groups 0..3, full
    if (wv < 3) {
        run_group(wv + 4, 0, TT - S, true);    // groups 4..6, head
    } else {
        run_group(4, TT - S, TT, true);        // group 4..6 tails
        run_group(5, TT - S, TT, true);
        run_group(6, TT - S, TT, true);
    }
    __syncthreads();

    // ======== phase 3: out[m][a] = sum_c M[c][m] * M[c][a], a < 4 ==========
    if (k < D2) {
        const float m0 = u.Ms[0][k], m1 = u.Ms[1][k], m2 = u.Ms[2][k];
        float4 o4;
        o4.x = m0 * u.Ms[0][0] + m1 * u.Ms[1][0] + m2 * u.Ms[2][0];
        o4.y = m0 * u.Ms[0][1] + m1 * u.Ms[1][1] + m2 * u.Ms[2][1];
        o4.z = m0 * u.Ms[0][2] + m1 * u.Ms[1][2] + m2 * u.Ms[2][2];
        o4.w = m0 * u.Ms[0][3] + m1 * u.Ms[1][3] + m2 * u.Ms[2][3];
        reinterpret_cast<float4*>(out)[bn * D2 + k] = o4;   // 16B-aligned
    }
}

extern "C" void kernel_launch(void* const* d_in, const int* in_sizes, int n_in,
                              void* d_out, int out_size, void* d_ws, size_t ws_size,
                              hipStream_t stream) {
    (void)in_sizes; (void)n_in; (void)out_size; (void)ws_size;
    const float* coords = (const float*)d_in[0];
    const int*   types  = (const int*)  d_in[1];
    const float* W0 = (const float*)d_in[2];
    const float* B0 = (const float*)d_in[3];
    const float* W1 = (const float*)d_in[4];
    const float* B1 = (const float*)d_in[5];
    const float* W2 = (const float*)d_in[6];
    const float* B2 = (const float*)d_in[7];
    float* out = (float*)d_out;

    _Float16* W1h = (_Float16*)d_ws;                 // 25600 halves (CT-scaled)
    _Float16* W2h = (_Float16*)d_ws + W1H_HALVES;    // 102400 halves (CT-scaled)

    const int cvt_dwords = (W1H_HALVES + W2H_HALVES) / 2;      // 64000
    cvt_kernel<<<(cvt_dwords + 255) / 256, 256, 0, stream>>>(
        W1, W2, (unsigned int*)d_ws);

    feat_kernel<<<64 * NATOM, 256, 0, stream>>>(
        coords, types, W0, B0, B1, B2, W1h, W2h, out);
}

// Round 3
// 177.677 us; speedup vs baseline: 1.0787x; 1.0787x over previous
//
#include <hip/hip_runtime.h>
#include <hip/hip_bf16.h>

#define NATOM 128
#define NB    127
#define D0    25
#define D1    50
#define D2    100
#define H0STR 40     // halves; 80 B rows -> b128 A-frag reads 2-way (free)
#define H1STR 56     // halves; 112 B rows; cols 50..55 pad (lq=3 K-frag remapped)
#define MROWS 176    // worst case: sum 16*ceil(c_t/16) = 176 rows
#define W1H_HALVES (16 * 50 * 32)     // 25600  (K 25 -> 32, zero-padded)
#define W2H_HALVES (16 * 100 * 64)    // 102400 (K 50 -> 64, zero-padded)
#define CT 2.8853900817779268f        // 2*log2(e); tanh(x)=1-2/(exp2(CT*x)+1)

typedef _Float16 half8 __attribute__((ext_vector_type(8)));  // 8 fp16 = 4 VGPRs
typedef __attribute__((ext_vector_type(4))) float f32x4;

__device__ __forceinline__ float exp2_hw(float x) {
#if defined(__has_builtin)
#if __has_builtin(__builtin_amdgcn_exp2f)
    return __builtin_amdgcn_exp2f(x);        // raw v_exp_f32 (exp2 semantics)
#else
    return __expf(0.6931471805599453f * x);
#endif
#else
    return __expf(0.6931471805599453f * x);
#endif
}

// tanh(x) with PRE-SCALED argument y = CT*x (CT folded into weights/bias):
// tanh(x) = 1 - 2/(exp2(y)+1). exp2->add->rcp->fma.
__device__ __forceinline__ float tanh_pre(float y) {
    float e = exp2_hw(y);
    return 1.0f - 2.0f * __builtin_amdgcn_rcpf(e + 1.0f);
}

// ---- one-shot (per launch) fp32 -> fp16 weight repack into d_ws ----------
// W1h[idx][o][k32], W2h[idx][o][k64]; values pre-scaled by CT so the MFMA
// accumulator is already the exp2 argument. |CT*W| <= 0.6 -> fp16-safe.
__global__ void cvt_kernel(const float* __restrict__ W1,
                           const float* __restrict__ W2,
                           unsigned int* __restrict__ ws) {
    const int i = blockIdx.x * 256 + threadIdx.x;   // dword index
    if (i >= (W1H_HALVES + W2H_HALVES) / 2) return;
    float v0, v1;
    if (i < W1H_HALVES / 2) {
        const int s = 2 * i;
        const int row = s >> 5, kk = s & 31;        // row = idx*50 + o
        const float* base = W1 + row * D0;
        v0 = (kk < D0) ? base[kk] : 0.f;
        v1 = (kk + 1 < D0) ? base[kk + 1] : 0.f;
    } else {
        const int s = 2 * i - W1H_HALVES;
        const int row = s >> 6, kk = s & 63;        // row = idx*100 + o
        const float* base = W2 + row * D1;
        v0 = (kk < D1) ? base[kk] : 0.f;
        v1 = (kk + 1 < D1) ? base[kk + 1] : 0.f;
    }
    union { _Float16 h[2]; unsigned int u; } cv;
    cv.h[0] = (_Float16)(CT * v0);                  // RNE, range-safe
    cv.h[1] = (_Float16)(CT * v1);
    ws[i] = cv.u;
}

__global__ __launch_bounds__(256, 1) void feat_kernel(
    const float* __restrict__ coords,
    const int*   __restrict__ types,
    const float* __restrict__ W0, const float* __restrict__ B0,
    const float* __restrict__ B1, const float* __restrict__ B2,
    const _Float16* __restrict__ W1h, const _Float16* __restrict__ W2h,
    float* __restrict__ out)
{
    // 19712 + 14080 + 2112 + 400 + 800 + 32 = 37136 B -> 4 blocks/CU, 16 waves
    __shared__ __attribute__((aligned(16))) _Float16 H1f[MROWS][H1STR];
    // H0f's last read is before the 2a->2b barrier; Ms is written only in 2b.
    __shared__ union __attribute__((aligned(16))) {
        _Float16 H0f[MROWS][H0STR];
        float    Ms[3][112];
    } u;
    // env_a as 3 fp32 planes: rows mq..mq+3 = one b128 per component in 2b.
    __shared__ __attribute__((aligned(16))) float Ep3[3][MROWS];
    __shared__ _Float16 PB1[4][D1];     // CT-scaled fp16 biases
    __shared__ _Float16 PB2[4][D2];
    __shared__ int cnt[2][4];           // per-wave type counts (waves 0,1)

    const int bn = blockIdx.x;    // b*128 + n
    const int b  = bn >> 7;
    const int n  = bn & 127;
    const int k  = threadIdx.x;   // 0..255
    const int wv = k >> 6;        // wave 0..3
    const int lq = (k >> 4) & 3;  // quad within wave
    const int ln = k & 15;
    const int lane = k & 63;
    const int tn  = types[n];

    // ---- stage CT-scaled fp16 bias tables for this center type
    for (int i = k; i < 600; i += 256) {
        if (i < 200) PB1[0][i] = (_Float16)(CT * B1[tn * 200 + i]);
        else         PB2[0][i - 200] = (_Float16)(CT * B2[tn * 400 + (i - 200)]);
    }

    // ---- ballot-based type counts + stable ranks.
    // Threads 128+i mirror thread i's neighbor: waves {0,2} and {1,3} have
    // identical lane<->neighbor maps, so ranks come free for both halves.
    int tj = -1, j0 = 0, jj = -1;
    if (k < NB) jj = k;
    else if (k >= 128 && k < 128 + NB) jj = k - 128;
    if (jj >= 0) { j0 = jj + (jj >= n ? 1 : 0); tj = types[j0]; }
    const unsigned long long bm0 = __ballot(tj == 0);
    const unsigned long long bm1 = __ballot(tj == 1);
    const unsigned long long bm2 = __ballot(tj == 2);
    const unsigned long long bm3 = __ballot(tj == 3);
    if (lane == 0 && wv < 2) {
        cnt[wv][0] = __popcll(bm0); cnt[wv][1] = __popcll(bm1);
        cnt[wv][2] = __popcll(bm2); cnt[wv][3] = __popcll(bm3);
    }
    int sameBefore = 0;
    if (jj >= 0) {
        const unsigned long long mym =
            (tj == 0) ? bm0 : (tj == 1) ? bm1 : (tj == 2) ? bm2 : bm3;
        sameBefore = __popcll(mym & ((1ULL << lane) - 1ULL));
    }
    __syncthreads();

    const int c0 = cnt[0][0] + cnt[1][0];
    const int c1 = cnt[0][1] + cnt[1][1];
    const int c2 = cnt[0][2] + cnt[1][2];
    const int c3 = cnt[0][3] + cnt[1][3];
    const int ps1 = (c0 + 15) & ~15;
    const int ps2 = ps1 + ((c1 + 15) & ~15);
    const int ps3 = ps2 + ((c2 + 15) & ~15);

    // ======== phase 1: geometry + layer 0, split across ALL 256 threads ====
    // A-half (k<128): Ep + h0[0..11] (3 uint2 stores, dwords 0..5).
    // B-half: h0[12..24] + K-pad (5 uint2 stores, dwords 6..15). No b16/b32.
    if (jj >= 0) {
        const int idx = (tn << 2) | tj;
        const int pst = (tj == 0) ? 0 : (tj == 1) ? ps1 : (tj == 2) ? ps2 : ps3;
        const int pr  = pst + sameBefore + ((wv & 1) ? cnt[0][tj] : 0);

        const float cx = coords[(b * NATOM + n) * 3 + 0];
        const float cy = coords[(b * NATOM + n) * 3 + 1];
        const float cz = coords[(b * NATOM + n) * 3 + 2];
        const float dx = cx - coords[(b * NATOM + j0) * 3 + 0];
        const float dy = cy - coords[(b * NATOM + j0) * 3 + 1];
        const float dz = cz - coords[(b * NATOM + j0) * 3 + 2];
        const float d2   = dx * dx + dy * dy + dz * dz;
        const float inv  = rsqrtf(d2);         // 1/d (= env_r)
        const float inv2 = inv * inv;
        const float invc = CT * inv;           // pre-scaled tanh argument

        const float* w  = W0 + idx * D0;
        const float* bb = B0 + idx * D0;
        uint2* dst2 = (uint2*)&u.H0f[pr][0];

        if (k < 128) {                         // A-half: Ep planes + h0[0..11]
            Ep3[0][pr] = dx * inv2;
            Ep3[1][pr] = dy * inv2;
            Ep3[2][pr] = dz * inv2;
            unsigned int dv[6];
            #pragma unroll
            for (int o = 0; o < 12; o += 2) {
                union { _Float16 h[2]; unsigned int v; } cv;
                cv.h[0] = (_Float16)tanh_pre(fmaf(w[o], invc, CT * bb[o]));
                cv.h[1] = (_Float16)tanh_pre(fmaf(w[o + 1], invc, CT * bb[o + 1]));
                dv[o >> 1] = cv.v;
            }
            uint2 s0; s0.x = dv[0]; s0.y = dv[1]; dst2[0] = s0;
            uint2 s1; s1.x = dv[2]; s1.y = dv[3]; dst2[1] = s1;
            uint2 s2; s2.x = dv[4]; s2.y = dv[5]; dst2[2] = s2;
        } else {                               // B-half: h0[12..24] + K-pad
            _Float16 hv[13];
            #pragma unroll
            for (int q = 0; q < 13; ++q)
                hv[q] = (_Float16)tanh_pre(fmaf(w[12 + q], invc, CT * bb[12 + q]));
            unsigned int dv[7];
            #pragma unroll
            for (int q = 0; q < 6; ++q) {
                union { _Float16 h[2]; unsigned int v; } cv;
                cv.h[0] = hv[2 * q]; cv.h[1] = hv[2 * q + 1];
                dv[q] = cv.v;                  // dwords 6..11 (cols 12..23)
            }
            { union { _Float16 h[2]; unsigned int v; } cl;
              cl.h[0] = hv[12]; cl.h[1] = (_Float16)0.f; dv[6] = cl.v; } // col 24 + pad
            uint2 s3; s3.x = dv[0]; s3.y = dv[1]; dst2[3] = s3;
            uint2 s4; s4.x = dv[2]; s4.y = dv[3]; dst2[4] = s4;
            uint2 s5; s5.x = dv[4]; s5.y = dv[5]; dst2[5] = s5;
            uint2 s6; s6.x = dv[6]; s6.y = 0u;   dst2[6] = s6;   // cols 24..27
            uint2 s7; s7.x = 0u;    s7.y = 0u;   dst2[7] = s7;   // cols 28..31
        }
    }
    // ---- pad-ROW zeroing: <=49 rows, spare B-side threads. Zero h0 K-range
    // (cols 0..31; 32..39 never read) + Ep planes (Mc mask).
    if (k >= 128 && k < 255) {
        const int i = k - 128;
        const int p0 = ((c0 + 15) & ~15) - c0;
        const int p1 = ((c1 + 15) & ~15) - c1;
        const int p2 = ((c2 + 15) & ~15) - c2;
        const int p3 = ((c3 + 15) & ~15) - c3;
        int row = -1;
        if (i < p0)                row = c0 + i;
        else if (i < p0 + p1)      row = ps1 + c1 + (i - p0);
        else if (i < p0 + p1 + p2) row = ps2 + c2 + (i - p0 - p1);
        else if (i < p0 + p1 + p2 + p3)
                                   row = ps3 + c3 + (i - p0 - p1 - p2);
        if (row >= 0) {
            uint2* pz = (uint2*)&u.H0f[row][0];
            const uint2 z2 = {0u, 0u};
            #pragma unroll
            for (int q = 0; q < 8; ++q) pz[q] = z2;
            Ep3[0][row] = 0.f; Ep3[1][row] = 0.f; Ep3[2][row] = 0.f;
        }
    }
    __syncthreads();

    // ======== phase 2a: layer 1 via MFMA (25 -> 50), K padded to 32 ========
    // Always-store (ov1 ? h : 0) fills H1f pad cols 50..55; cols 56..63 of
    // the logical K=64 don't exist (lq=3 B-frag rows of W2h are zero).
    {
        const int o1   = wv * 16 + ln;         // 0..63
        const bool ov1 = (o1 < D1);
        const bool st1 = (o1 < H1STR);         // only cols 0..55 exist
        const int o1c  = ov1 ? o1 : 0;         // clamp: pad lanes load row 0
        const int rres1 = ((o1 < D0) ? o1 : (o1 - D0)) & 31;  // in-row clamp
        #pragma unroll
        for (int t = 0; t < 4; ++t) {
            const int cnt_t = (t == 0) ? c0 : (t == 1) ? c1 : (t == 2) ? c2 : c3;
            if (cnt_t == 0) continue;
            const int ps  = (t == 0) ? 0 : (t == 1) ? ps1 : (t == 2) ? ps2 : ps3;
            const int idx = (tn << 2) | t;
            const half8 bf =
                *(const half8*)(W1h + (idx * 50 + o1c) * 32 + lq * 8);
            const float b1v = ov1 ? (float)PB1[t][o1c] : 0.f;
            const int mtiles = (cnt_t + 15) >> 4;
            for (int mt = 0; mt < mtiles; ++mt) {
                const int mb = ps + mt * 16;
                const half8 af = *(const half8*)(&u.H0f[mb + ln][lq * 8]);
                f32x4 d = {b1v, b1v, b1v, b1v};        // bias as C-operand
                d = __builtin_amdgcn_mfma_f32_16x16x32_f16(af, bf, d, 0, 0, 0);
                #pragma unroll
                for (int r = 0; r < 4; ++r) {
                    const int m = mb + lq * 4 + r;
                    const _Float16 h16 =
                        (_Float16)tanh_pre(d[r]) + u.H0f[m][rres1];
                    if (st1) H1f[m][o1] = ov1 ? h16 : (_Float16)0.f;
                }
            }
        }
    }
    __syncthreads();
    // ---- from here on, u is Ms; H0f is dead (all reads were pre-barrier)

    // ======== phase 2b: layer 2 via MFMA (50 -> 100) + fused M-reduce ======
    // Single pass over m-tiles; wave wv computes BOTH its groups (wv, wv+4)
    // per tile so the af/Ep reads are shared. Plain stores (each o<100 once).
    {
        const bool has1 = (wv < 3);             // group wv+4 exists (4..6)
        const int oA  = wv * 16 + ln;           // group-0 neuron (<64, real)
        const int oB  = (wv + 4) * 16 + ln;     // group-1 neuron (may pad)
        const int ocB = (oB < D2) ? oB : (D2 - 1);
        const int rrA = (oA >= D1) ? (oA - D1) : oA;    // residual columns
        const int rrB = (ocB >= D1) ? (ocB - D1) : ocB;
        const int off1 = (lq == 3) ? 32 : (32 + lq * 8); // lq=3 K-rows of W2h=0
        float McA0 = 0.f, McA1 = 0.f, McA2 = 0.f;
        float McB0 = 0.f, McB1 = 0.f, McB2 = 0.f;
        #pragma unroll
        for (int t = 0; t < 4; ++t) {
            const int cnt_t = (t == 0) ? c0 : (t == 1) ? c1 : (t == 2) ? c2 : c3;
            if (cnt_t == 0) continue;
            const int ps  = (t == 0) ? 0 : (t == 1) ? ps1 : (t == 2) ? ps2 : ps3;
            const int idx = (tn << 2) | t;
            const _Float16* wrA = W2h + (idx * 100 + oA) * 64;
            const half8 bfA0 = *(const half8*)(wrA + lq * 8);
            const half8 bfA1 = *(const half8*)(wrA + 32 + lq * 8);
            const float bA = (float)PB2[t][oA];
            const _Float16* wrB = W2h + (idx * 100 + ocB) * 64;
            const half8 bfB0 = *(const half8*)(wrB + lq * 8);
            const half8 bfB1 = *(const half8*)(wrB + 32 + lq * 8);
            const float bB = (float)PB2[t][ocB];
            const int mtiles = (cnt_t + 15) >> 4;
            for (int mt = 0; mt < mtiles; ++mt) {
                const int mb = ps + mt * 16;
                const _Float16* arow = &H1f[mb + ln][0];
                const half8 af0 = *(const half8*)(arow + lq * 8);
                const half8 af1 = *(const half8*)(arow + off1);
                const int mq = mb + lq * 4;
                const f32x4 ex = *(const f32x4*)&Ep3[0][mq];
                const f32x4 ey = *(const f32x4*)&Ep3[1][mq];
                const f32x4 ez = *(const f32x4*)&Ep3[2][mq];
                {
                    f32x4 d = {bA, bA, bA, bA};        // bias as C-operand
                    d = __builtin_amdgcn_mfma_f32_16x16x32_f16(af0, bfA0, d, 0, 0, 0);
                    d = __builtin_amdgcn_mfma_f32_16x16x32_f16(af1, bfA1, d, 0, 0, 0);
                    #pragma unroll
                    for (int r = 0; r < 4; ++r) {      // C/D: row = quad*4+r
                        const float gv =
                            tanh_pre(d[r]) + (float)H1f[mq + r][rrA];
                        McA0 = fmaf(ex[r], gv, McA0);
                        McA1 = fmaf(ey[r], gv, McA1);
                        McA2 = fmaf(ez[r], gv, McA2);
                    }
                }
                if (has1) {
                    f32x4 d = {bB, bB, bB, bB};
                    d = __builtin_amdgcn_mfma_f32_16x16x32_f16(af0, bfB0, d, 0, 0, 0);
                    d = __builtin_amdgcn_mfma_f32_16x16x32_f16(af1, bfB1, d, 0, 0, 0);
                    #pragma unroll
                    for (int r = 0; r < 4; ++r) {
                        const float gv =
                            tanh_pre(d[r]) + (float)H1f[mq + r][rrB];
                        McB0 = fmaf(ex[r], gv, McB0);
                        McB1 = fmaf(ey[r], gv, McB1);
                        McB2 = fmaf(ez[r], gv, McB2);
                    }
                }
            }
        }
        // reduce across the 4 quads (rows); lanes differ only in lq
        McA0 += __shfl_xor(McA0, 16, 64); McA1 += __shfl_xor(McA1, 16, 64);
        McA2 += __shfl_xor(McA2, 16, 64);
        McA0 += __shfl_xor(McA0, 32, 64); McA1 += __shfl_xor(McA1, 32, 64);
        McA2 += __shfl_xor(McA2, 32, 64);
        if (lq == 0) {                          // oA <= 63 < 100: always real
            u.Ms[0][oA] = McA0; u.Ms[1][oA] = McA1; u.Ms[2][oA] = McA2;
        }
        if (has1) {
            McB0 += __shfl_xor(McB0, 16, 64); McB1 += __shfl_xor(McB1, 16, 64);
            McB2 += __shfl_xor(McB2, 16, 64);
            McB0 += __shfl_xor(McB0, 32, 64); McB1 += __shfl_xor(McB1, 32, 64);
            McB2 += __shfl_xor(McB2, 32, 64);
            if (lq == 0 && oB < D2) {
                u.Ms[0][oB] = McB0; u.Ms[1][oB] = McB1; u.Ms[2][oB] = McB2;
            }
        }
    }
    __syncthreads();

    // ======== phase 3: out[m][a] = sum_c M[c][m] * M[c][a], a < 4 ==========
    if (k < D2) {
        const float m0 = u.Ms[0][k], m1 = u.Ms[1][k], m2 = u.Ms[2][k];
        float4 o4;
        o4.x = m0 * u.Ms[0][0] + m1 * u.Ms[1][0] + m2 * u.Ms[2][0];
        o4.y = m0 * u.Ms[0][1] + m1 * u.Ms[1][1] + m2 * u.Ms[2][1];
        o4.z = m0 * u.Ms[0][2] + m1 * u.Ms[1][2] + m2 * u.Ms[2][2];
        o4.w = m0 * u.Ms[0][3] + m1 * u.Ms[1][3] + m2 * u.Ms[2][3];
        reinterpret_cast<float4*>(out)[bn * D2 + k] = o4;   // 16B-aligned
    }
}

extern "C" void kernel_launch(void* const* d_in, const int* in_sizes, int n_in,
                              void* d_out, int out_size, void* d_ws, size_t ws_size,
                              hipStream_t stream) {
    (void)in_sizes; (void)n_in; (void)out_size; (void)ws_size;
    const float* coords = (const float*)d_in[0];
    const int*   types  = (const int*)  d_in[1];
    const float* W0 = (const float*)d_in[2];
    const float* B0 = (const float*)d_in[3];
    const float* W1 = (const float*)d_in[4];
    const float* B1 = (const float*)d_in[5];
    const float* W2 = (const float*)d_in[6];
    const float* B2 = (const float*)d_in[7];
    float* out = (float*)d_out;

    _Float16* W1h = (_Float16*)d_ws;                 // 25600 halves (CT-scaled)
    _Float16* W2h = (_Float16*)d_ws + W1H_HALVES;    // 102400 halves (CT-scaled)

    const int cvt_dwords = (W1H_HALVES + W2H_HALVES) / 2;      // 64000
    cvt_kernel<<<(cvt_dwords + 255) / 256, 256, 0, stream>>>(
        W1, W2, (unsigned int*)d_ws);

    feat_kernel<<<64 * NATOM, 256, 0, stream>>>(
        coords, types, W0, B0, B1, B2, W1h, W2h, out);
}